// Round 1
// baseline (526.698 us; speedup 1.0000x reference)
//
#include <hip/hip_runtime.h>
#include <math.h>

// Problem constants (from reference)
#define B_   16
#define T_   64
#define N_   22
#define D_   64
#define K_   4
#define E_   8
#define DT_  5
#define H_   64
#define TW   59            // T - 2*dt_half - 1 = 64 - 5 = 59 time steps (t=2..60)
#define M_   (B_ * TW)     // 944 flattened (b,t) rows
#define FIN  (DT_ * K_ * D_)  // 1280
#define MT   64            // m-tile rows per block
#define NTILES ((M_ + MT - 1) / MT)   // 15

// Kernel A: for one (n, e, m-tile), compute err[m, n, e] for 64 rows.
// 3-layer MLP: h1 = relu(F @ W1 + b1); h2 = relu(h1 @ W2 + b2);
// pred = h2 @ W3 + b3; err = mean_d (pred - y)^2.
// F is gathered on the fly from x: F[m, (dt*4+k)*64 + d] = x[b, t+dt, nb[n,k], d].
__global__ __launch_bounds__(256) void moe_err_kernel(
    const float* __restrict__ x, const int* __restrict__ nb,
    const float* __restrict__ W1, const float* __restrict__ b1,
    const float* __restrict__ W2, const float* __restrict__ b2,
    const float* __restrict__ W3, const float* __restrict__ b3,
    float* __restrict__ err_ws)
{
    const int tid = threadIdx.x;
    const int tx  = tid & 15;        // output col group
    const int ty  = tid >> 4;        // output row group
    const int blk = blockIdx.x;
    const int mtile = blk % NTILES;
    const int ne    = blk / NTILES;  // 0..175
    const int n = ne >> 3, e = ne & 7;
    const int m0 = mtile * MT;

    // As: A-operand tile (rows x 64 K-elems), stride 68 -> rows 16B-aligned,
    // scalar column reads alias at most 2-way (free). Reused as h1/h2 buffer.
    __shared__ float As[64][68];
    __shared__ float Ws[64][64];

    // neighbor node indices for this n
    int nn[K_];
    #pragma unroll
    for (int k = 0; k < K_; ++k) nn[k] = nb[n * K_ + k];

    // per-v load-row info (row = tid/16 + 16v), fixed across K-chunks
    int rb[4], rt[4];
    bool rvalid[4];
    #pragma unroll
    for (int v = 0; v < 4; ++v) {
        int row = (tid >> 4) + 16 * v;
        int m = m0 + row;
        rvalid[v] = (m < M_);
        int mm = rvalid[v] ? m : 0;
        rb[v] = mm / TW;
        rt[v] = mm % TW;
    }
    const int c4 = tid & 15;   // float4 column within a 64-wide chunk

    float acc[4][4];
    #pragma unroll
    for (int r = 0; r < 4; ++r)
        #pragma unroll
        for (int c = 0; c < 4; ++c) acc[r][c] = 0.f;

    const float* W1ne = W1 + (size_t)(n * E_ + e) * FIN * H_;

    // ---------------- GEMM1: 20 K-chunks of 64 (one per (dt,k)) -------------
    for (int ch = 0; ch < 20; ++ch) {
        const int dt = ch >> 2, k = ch & 3;
        const int nk = nn[k];
        // stage F chunk: As[row][d] = x[b, t+dt, nk, d]
        #pragma unroll
        for (int v = 0; v < 4; ++v) {
            int row = (tid >> 4) + 16 * v;
            float4 val = make_float4(0.f, 0.f, 0.f, 0.f);
            if (rvalid[v]) {
                const float* p = x + (((size_t)(rb[v] * T_ + rt[v] + dt)) * N_ + nk) * D_ + c4 * 4;
                val = *(const float4*)p;
            }
            *(float4*)&As[row][c4 * 4] = val;
        }
        // stage W1 chunk: Ws[i][j] = W1[n,e, ch*64+i, j]
        const float* Wc = W1ne + (size_t)ch * 64 * H_;
        #pragma unroll
        for (int v = 0; v < 4; ++v) {
            int i = (tid >> 4) + 16 * v;
            *(float4*)&Ws[i][c4 * 4] = *(const float4*)(Wc + i * H_ + c4 * 4);
        }
        __syncthreads();
        #pragma unroll 8
        for (int kk = 0; kk < 64; ++kk) {
            float a0 = As[ty * 4 + 0][kk];
            float a1 = As[ty * 4 + 1][kk];
            float a2 = As[ty * 4 + 2][kk];
            float a3 = As[ty * 4 + 3][kk];
            float4 bv = *(const float4*)&Ws[kk][tx * 4];
            acc[0][0] += a0 * bv.x; acc[0][1] += a0 * bv.y; acc[0][2] += a0 * bv.z; acc[0][3] += a0 * bv.w;
            acc[1][0] += a1 * bv.x; acc[1][1] += a1 * bv.y; acc[1][2] += a1 * bv.z; acc[1][3] += a1 * bv.w;
            acc[2][0] += a2 * bv.x; acc[2][1] += a2 * bv.y; acc[2][2] += a2 * bv.z; acc[2][3] += a2 * bv.w;
            acc[3][0] += a3 * bv.x; acc[3][1] += a3 * bv.y; acc[3][2] += a3 * bv.z; acc[3][3] += a3 * bv.w;
        }
        __syncthreads();
    }

    // h1 = relu(acc + b1) -> As
    {
        const float4 bias1 = *(const float4*)(b1 + (size_t)(n * E_ + e) * H_ + tx * 4);
        #pragma unroll
        for (int r = 0; r < 4; ++r) {
            float4 h;
            h.x = fmaxf(acc[r][0] + bias1.x, 0.f);
            h.y = fmaxf(acc[r][1] + bias1.y, 0.f);
            h.z = fmaxf(acc[r][2] + bias1.z, 0.f);
            h.w = fmaxf(acc[r][3] + bias1.w, 0.f);
            *(float4*)&As[ty * 4 + r][tx * 4] = h;
        }
    }
    // stage W2
    {
        const float* W2ne = W2 + (size_t)(n * E_ + e) * H_ * H_;
        #pragma unroll
        for (int v = 0; v < 4; ++v) {
            int i = (tid >> 4) + 16 * v;
            *(float4*)&Ws[i][c4 * 4] = *(const float4*)(W2ne + i * H_ + c4 * 4);
        }
    }
    __syncthreads();

    // ---------------- GEMM2: 64x64x64 ----------------
    float acc2[4][4];
    #pragma unroll
    for (int r = 0; r < 4; ++r)
        #pragma unroll
        for (int c = 0; c < 4; ++c) acc2[r][c] = 0.f;
    #pragma unroll 8
    for (int kk = 0; kk < 64; ++kk) {
        float a0 = As[ty * 4 + 0][kk];
        float a1 = As[ty * 4 + 1][kk];
        float a2 = As[ty * 4 + 2][kk];
        float a3 = As[ty * 4 + 3][kk];
        float4 bv = *(const float4*)&Ws[kk][tx * 4];
        acc2[0][0] += a0 * bv.x; acc2[0][1] += a0 * bv.y; acc2[0][2] += a0 * bv.z; acc2[0][3] += a0 * bv.w;
        acc2[1][0] += a1 * bv.x; acc2[1][1] += a1 * bv.y; acc2[1][2] += a1 * bv.z; acc2[1][3] += a1 * bv.w;
        acc2[2][0] += a2 * bv.x; acc2[2][1] += a2 * bv.y; acc2[2][2] += a2 * bv.z; acc2[2][3] += a2 * bv.w;
        acc2[3][0] += a3 * bv.x; acc2[3][1] += a3 * bv.y; acc2[3][2] += a3 * bv.z; acc2[3][3] += a3 * bv.w;
    }
    __syncthreads();

    // h2 = relu(acc2 + b2) -> As
    {
        const float4 bias2 = *(const float4*)(b2 + (size_t)(n * E_ + e) * H_ + tx * 4);
        #pragma unroll
        for (int r = 0; r < 4; ++r) {
            float4 h;
            h.x = fmaxf(acc2[r][0] + bias2.x, 0.f);
            h.y = fmaxf(acc2[r][1] + bias2.y, 0.f);
            h.z = fmaxf(acc2[r][2] + bias2.z, 0.f);
            h.w = fmaxf(acc2[r][3] + bias2.w, 0.f);
            *(float4*)&As[ty * 4 + r][tx * 4] = h;
        }
    }
    // stage W3
    {
        const float* W3ne = W3 + (size_t)(n * E_ + e) * H_ * D_;
        #pragma unroll
        for (int v = 0; v < 4; ++v) {
            int i = (tid >> 4) + 16 * v;
            *(float4*)&Ws[i][c4 * 4] = *(const float4*)(W3ne + i * D_ + c4 * 4);
        }
    }
    __syncthreads();

    // ---------------- GEMM3: 64x64x64 -> pred ----------------
    #pragma unroll
    for (int r = 0; r < 4; ++r)
        #pragma unroll
        for (int c = 0; c < 4; ++c) acc[r][c] = 0.f;
    #pragma unroll 8
    for (int kk = 0; kk < 64; ++kk) {
        float a0 = As[ty * 4 + 0][kk];
        float a1 = As[ty * 4 + 1][kk];
        float a2 = As[ty * 4 + 2][kk];
        float a3 = As[ty * 4 + 3][kk];
        float4 bv = *(const float4*)&Ws[kk][tx * 4];
        acc[0][0] += a0 * bv.x; acc[0][1] += a0 * bv.y; acc[0][2] += a0 * bv.z; acc[0][3] += a0 * bv.w;
        acc[1][0] += a1 * bv.x; acc[1][1] += a1 * bv.y; acc[1][2] += a1 * bv.z; acc[1][3] += a1 * bv.w;
        acc[2][0] += a2 * bv.x; acc[2][1] += a2 * bv.y; acc[2][2] += a2 * bv.z; acc[2][3] += a2 * bv.w;
        acc[3][0] += a3 * bv.x; acc[3][1] += a3 * bv.y; acc[3][2] += a3 * bv.z; acc[3][3] += a3 * bv.w;
    }

    // err[m] = mean_d (pred - y)^2 ;  y[m,d] = x[b, t+2, n, d]
    const float4 bias3 = *(const float4*)(b3 + (size_t)(n * E_ + e) * D_ + tx * 4);
    #pragma unroll
    for (int r = 0; r < 4; ++r) {
        int m = m0 + ty * 4 + r;
        float s = 0.f;
        if (m < M_) {
            int b = m / TW, t = m % TW;
            float4 y4 = *(const float4*)(x + (((size_t)(b * T_ + t + 2)) * N_ + n) * D_ + tx * 4);
            float d0 = acc[r][0] + bias3.x - y4.x;
            float d1 = acc[r][1] + bias3.y - y4.y;
            float d2 = acc[r][2] + bias3.z - y4.z;
            float d3 = acc[r][3] + bias3.w - y4.w;
            s = d0 * d0 + d1 * d1 + d2 * d2 + d3 * d3;
        }
        // reduce over tx (lane bits 0..3 within the wave)
        s += __shfl_xor(s, 1);
        s += __shfl_xor(s, 2);
        s += __shfl_xor(s, 4);
        s += __shfl_xor(s, 8);
        if (tx == 0 && m < M_) {
            err_ws[((size_t)m * N_ + n) * E_ + e] = s * (1.f / 64.f);
        }
    }
}

// Kernel B: per (m,n): min/argmin over E, softmax(-err) KL; block-reduce + atomicAdd.
__global__ __launch_bounds__(256) void moe_reduce_kernel(
    const float* __restrict__ err_ws, float* __restrict__ out)
{
    const int tid = threadIdx.x;
    const int idx = blockIdx.x * 256 + tid;
    float v = 0.f;
    if (idx < M_ * N_) {
        const int m = idx / N_, n = idx % N_;
        const float* ep = err_ws + (size_t)idx * E_;
        float ev[E_];
        float mn = ep[0];
        int am = 0;
        ev[0] = mn;
        #pragma unroll
        for (int i = 1; i < E_; ++i) {
            ev[i] = ep[i];
            if (ev[i] < mn) { mn = ev[i]; am = i; }   // first-min, matches argmin
        }
        // p = softmax(-ev); max(-ev) = -mn
        float p[E_];
        float Z = 0.f;
        #pragma unroll
        for (int i = 0; i < E_; ++i) { p[i] = expf(mn - ev[i]); Z += p[i]; }
        const float invZ = 1.f / Z;
        float kl = 0.f;
        #pragma unroll
        for (int i = 0; i < E_; ++i) {
            float q = p[i] * invZ;
            kl += q * (logf(q + 1e-9f) + 2.0794415416798357f);  // log(8)
        }
        v = mn + 0.01f * kl;
        const int t = m % TW, b = m / TW;
        if (t == TW - 1 && n == N_ - 1) out[1 + b] = (float)am;  // expert_idx[:, -1, -1]
    }
    __shared__ float sd[256];
    sd[tid] = v;
    __syncthreads();
    for (int s = 128; s > 0; s >>= 1) {
        if (tid < s) sd[tid] += sd[tid + s];
        __syncthreads();
    }
    if (tid == 0) atomicAdd(out, sd[0] * (1.f / 20160.f));  // / B / (N-1) / (T-dt_half-2)
}

__global__ void init_out_kernel(float* out)
{
    if (threadIdx.x == 0) out[0] = 0.f;
}

extern "C" void kernel_launch(void* const* d_in, const int* in_sizes, int n_in,
                              void* d_out, int out_size, void* d_ws, size_t ws_size,
                              hipStream_t stream)
{
    const float* x  = (const float*)d_in[0];
    const int*   nb = (const int*)d_in[1];
    const float* W1 = (const float*)d_in[2];
    const float* b1 = (const float*)d_in[3];
    const float* W2 = (const float*)d_in[4];
    const float* b2 = (const float*)d_in[5];
    const float* W3 = (const float*)d_in[6];
    const float* b3 = (const float*)d_in[7];
    float* out = (float*)d_out;
    float* err_ws = (float*)d_ws;   // M_*N_*E_ floats = 664,576 B

    hipLaunchKernelGGL(init_out_kernel, dim3(1), dim3(64), 0, stream, out);
    hipLaunchKernelGGL(moe_err_kernel, dim3(N_ * E_ * NTILES), dim3(256), 0, stream,
                       x, nb, W1, b1, W2, b2, W3, b3, err_ws);
    const int nred = (M_ * N_ + 255) / 256;
    hipLaunchKernelGGL(moe_reduce_kernel, dim3(nred), dim3(256), 0, stream, err_ws, out);
}

// Round 2
// 390.723 us; speedup vs baseline: 1.3480x; 1.3480x over previous
//
#include <hip/hip_runtime.h>
#include <math.h>

// Problem constants
#define B_   16
#define T_   64
#define N_   22
#define D_   64
#define K_   4
#define E_   8
#define DT_  5
#define H_   64
#define TW   59                 // valid time steps (t=2..60 absolute)
#define M_   (B_ * TW)          // 944
#define NE_  (N_ * E_)          // 176
#define MT2  128                // rows per block
#define NT2  8                  // ceil(944/128)
#define NCHUNK 22               // 20 W1 chunks + W2 + W3
#define CHUNK_BYTES 16384       // 16 images x 1KB (64k x 64h, bf16 hi/lo)

typedef __attribute__((ext_vector_type(8))) short short8;
typedef __attribute__((ext_vector_type(4))) float float4v;

// wimg region in ws starts after err_ws
#define ERRWS_FLOATS (M_ * N_ * E_)        // 166,144 floats = 664,576 B (1KB aligned)
#define WIMG_OFF     ((size_t)ERRWS_FLOATS * 4)

// Round-to-nearest bf16 hi + truncated bf16 of residual. Combined rel err ~2^-16.
__device__ inline void split2(float f, unsigned& hi, unsigned& lo) {
    unsigned u = __float_as_uint(f);
    unsigned r = (u + 0x7fffu + ((u >> 16) & 1u)) & 0xffff0000u;
    hi = r >> 16;
    float rem = f - __uint_as_float(r);
    lo = __float_as_uint(rem) >> 16;
}

__device__ inline void split8(float4 a, float4 b, short8& hi, short8& lo) {
    float f[8] = {a.x, a.y, a.z, a.w, b.x, b.y, b.z, b.w};
    #pragma unroll
    for (int i = 0; i < 8; ++i) {
        unsigned h, l;
        split2(f[i], h, l);
        hi[i] = (short)h;
        lo[i] = (short)l;
    }
}

// ---------------------------------------------------------------------------
// Precompute: W1/W2/W3 -> bf16 hi/lo fragment images.
// Image layout per (ne, chunk): 16 images of 1KB: idx=((s2*4+cf)*2+hl),
// image[L][j(16B)] = split(W[k = s2*32+(L>>4)*8+j][col = cf*16+(L&15)]).
// One thread per (ne,chunk,s2,cf,L): 8 strided loads -> hi 16B + lo 16B.
__global__ __launch_bounds__(256) void wimg_kernel(
    const float* __restrict__ W1, const float* __restrict__ W2,
    const float* __restrict__ W3, char* __restrict__ wimg)
{
    int tid = blockIdx.x * 256 + threadIdx.x;   // < 176*22*2*4*64 = 1,982,464
    int L  = tid & 63;
    int cf = (tid >> 6) & 3;
    int s2 = (tid >> 8) & 1;
    int v  = tid >> 9;                          // 0..3871
    int chunk = v % NCHUNK;
    int ne    = v / NCHUNK;
    if (ne >= NE_) return;

    const float* src;
    if (chunk < 20)       src = W1 + ((size_t)ne * 1280 + (size_t)chunk * 64) * 64;
    else if (chunk == 20) src = W2 + (size_t)ne * 4096;
    else                  src = W3 + (size_t)ne * 4096;

    int k0  = s2 * 32 + (L >> 4) * 8;
    int col = cf * 16 + (L & 15);

    unsigned hi[8], lo[8];
    #pragma unroll
    for (int j = 0; j < 8; ++j) {
        split2(src[(size_t)(k0 + j) * 64 + col], hi[j], lo[j]);
    }
    uint4 h4, l4;
    h4.x = hi[0] | (hi[1] << 16); h4.y = hi[2] | (hi[3] << 16);
    h4.z = hi[4] | (hi[5] << 16); h4.w = hi[6] | (hi[7] << 16);
    l4.x = lo[0] | (lo[1] << 16); l4.y = lo[2] | (lo[3] << 16);
    l4.z = lo[4] | (lo[5] << 16); l4.w = lo[6] | (lo[7] << 16);

    char* base = wimg + ((size_t)(ne * NCHUNK + chunk)) * CHUNK_BYTES
                      + (size_t)((s2 * 4 + cf) * 2) * 1024 + (size_t)L * 16;
    *(uint4*)base          = h4;   // hi image
    *(uint4*)(base + 1024) = l4;   // lo image
}

// ---------------------------------------------------------------------------
// Main kernel: block = (ne, mtile of 128 rows). 4 waves, each 32 rows x 64 cols.
// GEMM1 (K=1280, 20 chunks): A direct-from-global fp32 x, split on the fly;
// B from pre-imaged LDS (register-prefetched 1 chunk ahead).
// GEMM2/3 (K=64): A from h1/h2 in padded LDS; same B path (chunks 20,21).
__global__ __launch_bounds__(256, 3) void moe_err_kernel(
    const float* __restrict__ x, const int* __restrict__ nb,
    const float* __restrict__ b1, const float* __restrict__ b2,
    const float* __restrict__ b3, const char* __restrict__ wimg,
    float* __restrict__ err_ws)
{
    const int tid = threadIdx.x;
    const int w   = tid >> 6;
    const int L   = tid & 63;
    const int blk = blockIdx.x;
    const int mt  = blk & 7;
    const int ne  = blk >> 3;
    const int n   = ne >> 3, e = ne & 7;

    __shared__ float h1s[128][68];                      // 34,816 B (pad 68: <=2-way)
    __shared__ __align__(16) unsigned char wbuf[CHUNK_BYTES];  // 16 KB

    const int lrow    = L & 15;
    const int dseg    = (L >> 4) * 8;
    const int rowbase = mt * MT2 + w * 32;

    // per-rowtile lane row -> (b,t) base pointer into x (fp32)
    const float* xrow[2];
    #pragma unroll
    for (int rt = 0; rt < 2; ++rt) {
        int m  = rowbase + rt * 16 + lrow;
        int mc = m < M_ ? m : M_ - 1;
        int b = mc / TW, t = mc % TW;
        xrow[rt] = x + ((size_t)(b * T_ + t) * N_) * D_;
    }

    int nn[K_];
    #pragma unroll
    for (int k = 0; k < K_; ++k) nn[k] = nb[n * K_ + k];

    const char* wsrc = wimg + (size_t)ne * NCHUNK * CHUNK_BYTES;

    // W chunk register prefetch: wave w stages images 4w..4w+3
    uint4 wreg[4];
    auto loadW = [&](int chunk) {
        const uint4* wp = (const uint4*)(wsrc + (size_t)chunk * CHUNK_BYTES);
        #pragma unroll
        for (int i = 0; i < 4; ++i) wreg[i] = wp[(w * 4 + i) * 64 + L];
    };
    auto storeW = [&]() {
        uint4* lp = (uint4*)wbuf;
        #pragma unroll
        for (int i = 0; i < 4; ++i) lp[(w * 4 + i) * 64 + L] = wreg[i];
    };
    auto bfrag = [&](int s2, int cf, int hl) -> short8 {
        return *(const short8*)(wbuf + (size_t)((s2 * 4 + cf) * 2 + hl) * 1024
                                     + (size_t)L * 16);
    };

    float4v acc1[2][4];
    #pragma unroll
    for (int rt = 0; rt < 2; ++rt)
        #pragma unroll
        for (int cf = 0; cf < 4; ++cf) acc1[rt][cf] = (float4v)0.f;

    loadW(0);

    // ---------------- GEMM1: 20 chunks of K=64 ----------------
    for (int c = 0; c < 20; ++c) {
        __syncthreads();            // prior chunk's B-reads done
        storeW();
        __syncthreads();            // images visible

        const int dt = c >> 2, kk = c & 3;
        const size_t off = ((size_t)dt * N_ + nn[kk]) * D_;

        float4 af[2][2][2];         // [rt][s2][half of 8 floats]
        #pragma unroll
        for (int rt = 0; rt < 2; ++rt)
            #pragma unroll
            for (int s2 = 0; s2 < 2; ++s2) {
                const float* p = xrow[rt] + off + s2 * 32 + dseg;
                af[rt][s2][0] = *(const float4*)p;
                af[rt][s2][1] = *(const float4*)(p + 4);
            }

        if (c < 19) loadW(c + 1);   // prefetch next chunk during MFMAs

        short8 ah[2][2], al[2][2];
        #pragma unroll
        for (int rt = 0; rt < 2; ++rt)
            #pragma unroll
            for (int s2 = 0; s2 < 2; ++s2)
                split8(af[rt][s2][0], af[rt][s2][1], ah[rt][s2], al[rt][s2]);

        #pragma unroll
        for (int s2 = 0; s2 < 2; ++s2)
            #pragma unroll
            for (int cf = 0; cf < 4; ++cf) {
                short8 bh = bfrag(s2, cf, 0);
                short8 bl = bfrag(s2, cf, 1);
                #pragma unroll
                for (int rt = 0; rt < 2; ++rt) {
                    acc1[rt][cf] = __builtin_amdgcn_mfma_f32_16x16x32_bf16(ah[rt][s2], bh, acc1[rt][cf], 0, 0, 0);
                    acc1[rt][cf] = __builtin_amdgcn_mfma_f32_16x16x32_bf16(ah[rt][s2], bl, acc1[rt][cf], 0, 0, 0);
                    acc1[rt][cf] = __builtin_amdgcn_mfma_f32_16x16x32_bf16(al[rt][s2], bh, acc1[rt][cf], 0, 0, 0);
                }
            }
    }

    // ---------------- h1 = relu(acc1 + b1) -> LDS; stage W2 ----------------
    loadW(20);
    __syncthreads();                // last chunk's B-reads done
    storeW();
    const int ccol = L & 15;
    const int qrow = (L >> 4) * 4;
    #pragma unroll
    for (int cf = 0; cf < 4; ++cf) {
        float bv = b1[(size_t)ne * H_ + cf * 16 + ccol];
        #pragma unroll
        for (int rt = 0; rt < 2; ++rt)
            #pragma unroll
            for (int reg = 0; reg < 4; ++reg) {
                int r = w * 32 + rt * 16 + qrow + reg;
                h1s[r][cf * 16 + ccol] = fmaxf(acc1[rt][cf][reg] + bv, 0.f);
            }
    }
    __syncthreads();                // W2 images + h1 visible

    // ---------------- GEMM2: h1 @ W2 (K=64) ----------------
    float4v acc2[2][4];
    #pragma unroll
    for (int rt = 0; rt < 2; ++rt)
        #pragma unroll
        for (int cf = 0; cf < 4; ++cf) acc2[rt][cf] = (float4v)0.f;

    {
        short8 ah[2][2], al[2][2];
        #pragma unroll
        for (int s2 = 0; s2 < 2; ++s2)
            #pragma unroll
            for (int rt = 0; rt < 2; ++rt) {
                const float* hp = &h1s[w * 32 + rt * 16 + lrow][s2 * 32 + dseg];
                split8(*(const float4*)hp, *(const float4*)(hp + 4), ah[rt][s2], al[rt][s2]);
            }
        loadW(21);                  // prefetch W3 during GEMM2 MFMAs
        #pragma unroll
        for (int s2 = 0; s2 < 2; ++s2)
            #pragma unroll
            for (int cf = 0; cf < 4; ++cf) {
                short8 bh = bfrag(s2, cf, 0);
                short8 bl = bfrag(s2, cf, 1);
                #pragma unroll
                for (int rt = 0; rt < 2; ++rt) {
                    acc2[rt][cf] = __builtin_amdgcn_mfma_f32_16x16x32_bf16(ah[rt][s2], bh, acc2[rt][cf], 0, 0, 0);
                    acc2[rt][cf] = __builtin_amdgcn_mfma_f32_16x16x32_bf16(ah[rt][s2], bl, acc2[rt][cf], 0, 0, 0);
                    acc2[rt][cf] = __builtin_amdgcn_mfma_f32_16x16x32_bf16(al[rt][s2], bh, acc2[rt][cf], 0, 0, 0);
                }
            }
    }

    // ---------------- h2 = relu(acc2 + b2) -> LDS; stage W3 ----------------
    __syncthreads();                // all waves done reading W2 images
    storeW();
    #pragma unroll
    for (int cf = 0; cf < 4; ++cf) {
        float bv = b2[(size_t)ne * H_ + cf * 16 + ccol];
        #pragma unroll
        for (int rt = 0; rt < 2; ++rt)
            #pragma unroll
            for (int reg = 0; reg < 4; ++reg) {
                int r = w * 32 + rt * 16 + qrow + reg;
                h1s[r][cf * 16 + ccol] = fmaxf(acc2[rt][cf][reg] + bv, 0.f);   // rows are wave-private
            }
    }
    __syncthreads();                // W3 images + h2 visible

    // ---------------- GEMM3: h2 @ W3 -> pred; err epilogue ----------------
    float4v acc3[2][4];
    #pragma unroll
    for (int rt = 0; rt < 2; ++rt)
        #pragma unroll
        for (int cf = 0; cf < 4; ++cf) acc3[rt][cf] = (float4v)0.f;

    {
        short8 ah[2][2], al[2][2];
        #pragma unroll
        for (int s2 = 0; s2 < 2; ++s2)
            #pragma unroll
            for (int rt = 0; rt < 2; ++rt) {
                const float* hp = &h1s[w * 32 + rt * 16 + lrow][s2 * 32 + dseg];
                split8(*(const float4*)hp, *(const float4*)(hp + 4), ah[rt][s2], al[rt][s2]);
            }
        #pragma unroll
        for (int s2 = 0; s2 < 2; ++s2)
            #pragma unroll
            for (int cf = 0; cf < 4; ++cf) {
                short8 bh = bfrag(s2, cf, 0);
                short8 bl = bfrag(s2, cf, 1);
                #pragma unroll
                for (int rt = 0; rt < 2; ++rt) {
                    acc3[rt][cf] = __builtin_amdgcn_mfma_f32_16x16x32_bf16(ah[rt][s2], bh, acc3[rt][cf], 0, 0, 0);
                    acc3[rt][cf] = __builtin_amdgcn_mfma_f32_16x16x32_bf16(ah[rt][s2], bl, acc3[rt][cf], 0, 0, 0);
                    acc3[rt][cf] = __builtin_amdgcn_mfma_f32_16x16x32_bf16(al[rt][s2], bh, acc3[rt][cf], 0, 0, 0);
                }
            }
    }

    float b3v[4];
    #pragma unroll
    for (int cf = 0; cf < 4; ++cf) b3v[cf] = b3[(size_t)ne * D_ + cf * 16 + ccol];

    #pragma unroll
    for (int rt = 0; rt < 2; ++rt) {
        float s[4] = {0.f, 0.f, 0.f, 0.f};
        #pragma unroll
        for (int reg = 0; reg < 4; ++reg) {
            int m  = rowbase + rt * 16 + qrow + reg;
            int mc = m < M_ ? m : M_ - 1;
            int b = mc / TW, t = mc % TW;
            const float* yp = x + ((size_t)(b * T_ + t + 2) * N_ + n) * D_;
            #pragma unroll
            for (int cf = 0; cf < 4; ++cf) {
                float d = acc3[rt][cf][reg] + b3v[cf] - yp[cf * 16 + ccol];
                s[reg] += d * d;
            }
        }
        #pragma unroll
        for (int reg = 0; reg < 4; ++reg) {
            s[reg] += __shfl_xor(s[reg], 1);
            s[reg] += __shfl_xor(s[reg], 2);
            s[reg] += __shfl_xor(s[reg], 4);
            s[reg] += __shfl_xor(s[reg], 8);
        }
        if (ccol == 0) {
            #pragma unroll
            for (int reg = 0; reg < 4; ++reg) {
                int m = rowbase + rt * 16 + qrow + reg;
                if (m < M_) err_ws[((size_t)m * N_ + n) * E_ + e] = s[reg] * (1.f / 64.f);
            }
        }
    }
}

// ---------------------------------------------------------------------------
// Reduce: per (m,n) min/argmin over E, softmax(-err) KL; block atomicAdd.
__global__ __launch_bounds__(256) void moe_reduce_kernel(
    const float* __restrict__ err_ws, float* __restrict__ out)
{
    const int tid = threadIdx.x;
    const int idx = blockIdx.x * 256 + tid;
    float v = 0.f;
    if (idx < M_ * N_) {
        const int m = idx / N_, n = idx % N_;
        const float* ep = err_ws + (size_t)idx * E_;
        float ev[E_];
        float mn = ep[0];
        int am = 0;
        ev[0] = mn;
        #pragma unroll
        for (int i = 1; i < E_; ++i) {
            ev[i] = ep[i];
            if (ev[i] < mn) { mn = ev[i]; am = i; }
        }
        float p[E_];
        float Z = 0.f;
        #pragma unroll
        for (int i = 0; i < E_; ++i) { p[i] = expf(mn - ev[i]); Z += p[i]; }
        const float invZ = 1.f / Z;
        float kl = 0.f;
        #pragma unroll
        for (int i = 0; i < E_; ++i) {
            float q = p[i] * invZ;
            kl += q * (logf(q + 1e-9f) + 2.0794415416798357f);  // log(8)
        }
        v = mn + 0.01f * kl;
        const int t = m % TW, b = m / TW;
        if (t == TW - 1 && n == N_ - 1) out[1 + b] = (float)am;
    }
    __shared__ float sd[256];
    sd[tid] = v;
    __syncthreads();
    for (int s = 128; s > 0; s >>= 1) {
        if (tid < s) sd[tid] += sd[tid + s];
        __syncthreads();
    }
    if (tid == 0) atomicAdd(out, sd[0] * (1.f / 20160.f));  // / B / (N-1) / (T-4)
}

__global__ void init_out_kernel(float* out)
{
    if (threadIdx.x == 0) out[0] = 0.f;
}

extern "C" void kernel_launch(void* const* d_in, const int* in_sizes, int n_in,
                              void* d_out, int out_size, void* d_ws, size_t ws_size,
                              hipStream_t stream)
{
    const float* x  = (const float*)d_in[0];
    const int*   nb = (const int*)d_in[1];
    const float* W1 = (const float*)d_in[2];
    const float* b1 = (const float*)d_in[3];
    const float* W2 = (const float*)d_in[4];
    const float* b2 = (const float*)d_in[5];
    const float* W3 = (const float*)d_in[6];
    const float* b3 = (const float*)d_in[7];
    float* out    = (float*)d_out;
    float* err_ws = (float*)d_ws;                    // 664,576 B
    char*  wimg   = (char*)d_ws + WIMG_OFF;          // 176*22*16KB = 63.4 MB

    hipLaunchKernelGGL(init_out_kernel, dim3(1), dim3(64), 0, stream, out);
    hipLaunchKernelGGL(wimg_kernel, dim3(7744), dim3(256), 0, stream, W1, W2, W3, wimg);
    hipLaunchKernelGGL(moe_err_kernel, dim3(NE_ * NT2), dim3(256), 0, stream,
                       x, nb, b1, b2, b3, wimg, err_ws);
    const int nred = (M_ * N_ + 255) / 256;
    hipLaunchKernelGGL(moe_reduce_kernel, dim3(nred), dim3(256), 0, stream, err_ws, out);
}

// Round 3
// 384.381 us; speedup vs baseline: 1.3703x; 1.0165x over previous
//
#include <hip/hip_runtime.h>
#include <math.h>

// Problem constants
#define B_   16
#define T_   64
#define N_   22
#define D_   64
#define K_   4
#define E_   8
#define DT_  5
#define H_   64
#define TW   59                 // valid time steps (t=2..60 absolute)
#define M_   (B_ * TW)          // 944
#define NE_  (N_ * E_)          // 176
#define MT2  128                // rows per block
#define NT2  8                  // ceil(944/128)
#define NCHUNK 22               // 20 W1 chunks + W2 + W3
#define CHUNK_BYTES 16384       // 16 images x 1KB (64k x 64h, bf16 hi/lo)
#define XTOT (B_ * T_ * N_ * D_)   // 1,441,792

typedef __attribute__((ext_vector_type(8))) short short8;
typedef __attribute__((ext_vector_type(4))) float float4v;

// workspace layout (16B-aligned sections)
#define ERRWS_BYTES  ((size_t)(M_ * N_ * E_) * 4)          // 664,576
#define WIMG_OFF     (ERRWS_BYTES)
#define WIMG_BYTES   ((size_t)NE_ * NCHUNK * CHUNK_BYTES)  // 63,438,848
#define XH_OFF       (WIMG_OFF + WIMG_BYTES)
#define XIMG_BYTES   ((size_t)XTOT * 2)                    // 2,883,584
#define XL_OFF       (XH_OFF + XIMG_BYTES)

// Round-to-nearest bf16 hi + truncated bf16 of residual. Combined rel err ~2^-16.
__device__ inline void split2(float f, unsigned& hi, unsigned& lo) {
    unsigned u = __float_as_uint(f);
    unsigned r = (u + 0x7fffu + ((u >> 16) & 1u)) & 0xffff0000u;
    hi = r >> 16;
    float rem = f - __uint_as_float(r);
    lo = __float_as_uint(rem) >> 16;
}

// ---------------------------------------------------------------------------
// Precompute 1: W1/W2/W3 -> bf16 hi/lo fragment images (same layout as R2).
__global__ __launch_bounds__(256) void wimg_kernel(
    const float* __restrict__ W1, const float* __restrict__ W2,
    const float* __restrict__ W3, char* __restrict__ wimg)
{
    int tid = blockIdx.x * 256 + threadIdx.x;
    int L  = tid & 63;
    int cf = (tid >> 6) & 3;
    int s2 = (tid >> 8) & 1;
    int v  = tid >> 9;
    int chunk = v % NCHUNK;
    int ne    = v / NCHUNK;
    if (ne >= NE_) return;

    const float* src;
    if (chunk < 20)       src = W1 + ((size_t)ne * 1280 + (size_t)chunk * 64) * 64;
    else if (chunk == 20) src = W2 + (size_t)ne * 4096;
    else                  src = W3 + (size_t)ne * 4096;

    int k0  = s2 * 32 + (L >> 4) * 8;
    int col = cf * 16 + (L & 15);

    unsigned hi[8], lo[8];
    #pragma unroll
    for (int j = 0; j < 8; ++j) {
        split2(src[(size_t)(k0 + j) * 64 + col], hi[j], lo[j]);
    }
    uint4 h4, l4;
    h4.x = hi[0] | (hi[1] << 16); h4.y = hi[2] | (hi[3] << 16);
    h4.z = hi[4] | (hi[5] << 16); h4.w = hi[6] | (hi[7] << 16);
    l4.x = lo[0] | (lo[1] << 16); l4.y = lo[2] | (lo[3] << 16);
    l4.z = lo[4] | (lo[5] << 16); l4.w = lo[6] | (lo[7] << 16);

    char* base = wimg + ((size_t)(ne * NCHUNK + chunk)) * CHUNK_BYTES
                      + (size_t)((s2 * 4 + cf) * 2) * 1024 + (size_t)L * 16;
    *(uint4*)base          = h4;
    *(uint4*)(base + 1024) = l4;
}

// ---------------------------------------------------------------------------
// Precompute 2: x -> bf16 hi/lo images (same linear layout as x).
__global__ __launch_bounds__(256) void xsplit_kernel(
    const float* __restrict__ x, short* __restrict__ xh, short* __restrict__ xl)
{
    int i = (blockIdx.x * 256 + threadIdx.x) * 4;
    if (i >= XTOT) return;
    float4 v = *(const float4*)(x + i);
    unsigned h0, h1, h2, h3, l0, l1, l2, l3;
    split2(v.x, h0, l0); split2(v.y, h1, l1);
    split2(v.z, h2, l2); split2(v.w, h3, l3);
    uint2 hp, lp;
    hp.x = h0 | (h1 << 16); hp.y = h2 | (h3 << 16);
    lp.x = l0 | (l1 << 16); lp.y = l2 | (l3 << 16);
    *(uint2*)(xh + i) = hp;
    *(uint2*)(xl + i) = lp;
}

// ---------------------------------------------------------------------------
// Main kernel: block = (ne, mtile of 128 rows). 4 waves, each 32 rows x 64 cols.
// GEMM1: A direct from pre-split xh/xl (16B global loads, L2-hot); B from
// pre-imaged LDS with register prefetch. GEMM2/3: A from pre-split h images
// in padded LDS (ds_read_b128); same B path.
__global__ __launch_bounds__(256, 3) void moe_err_kernel(
    const float* __restrict__ x, const short* __restrict__ xh,
    const short* __restrict__ xl, const int* __restrict__ nb,
    const float* __restrict__ b1, const float* __restrict__ b2,
    const float* __restrict__ b3, const char* __restrict__ wimg,
    float* __restrict__ err_ws)
{
    const int tid = threadIdx.x;
    const int w   = tid >> 6;
    const int L   = tid & 63;
    const int blk = blockIdx.x;
    const int mt  = blk & 7;
    const int ne  = blk >> 3;
    const int n   = ne >> 3, e = ne & 7;

    __shared__ __align__(16) unsigned char wbuf[CHUNK_BYTES];   // 16 KB
    __shared__ __align__(16) short h1h[128][72];                // 18,432 B (stride 144B: 2-way max)
    __shared__ __align__(16) short h1l[128][72];                // 18,432 B

    const int lrow    = L & 15;
    const int dseg    = (L >> 4) * 8;
    const int rowbase = mt * MT2 + w * 32;

    // per-rowtile lane row -> base (in elements) into x images
    const short* xhrow[2];
    const short* xlrow[2];
    #pragma unroll
    for (int rt = 0; rt < 2; ++rt) {
        int m  = rowbase + rt * 16 + lrow;
        int mc = m < M_ ? m : M_ - 1;
        int b = mc / TW, t = mc % TW;
        size_t base = (size_t)(b * T_ + t) * N_ * D_;
        xhrow[rt] = xh + base;
        xlrow[rt] = xl + base;
    }

    int nn[K_];
    #pragma unroll
    for (int k = 0; k < K_; ++k) nn[k] = nb[n * K_ + k];

    const char* wsrc = wimg + (size_t)ne * NCHUNK * CHUNK_BYTES;

    // W chunk register prefetch: wave w stages images 4w..4w+3
    uint4 wreg[4];
    auto loadW = [&](int chunk) {
        const uint4* wp = (const uint4*)(wsrc + (size_t)chunk * CHUNK_BYTES);
        #pragma unroll
        for (int i = 0; i < 4; ++i) wreg[i] = wp[(w * 4 + i) * 64 + L];
    };
    auto storeW = [&]() {
        uint4* lp = (uint4*)wbuf;
        #pragma unroll
        for (int i = 0; i < 4; ++i) lp[(w * 4 + i) * 64 + L] = wreg[i];
    };
    auto bfrag = [&](int s2, int cf, int hl) -> short8 {
        return *(const short8*)(wbuf + (size_t)((s2 * 4 + cf) * 2 + hl) * 1024
                                     + (size_t)L * 16);
    };

    float4v acc1[2][4];
    #pragma unroll
    for (int rt = 0; rt < 2; ++rt)
        #pragma unroll
        for (int cf = 0; cf < 4; ++cf) acc1[rt][cf] = (float4v)0.f;

    loadW(0);

    // ---------------- GEMM1: 20 chunks of K=64 ----------------
    for (int c = 0; c < 20; ++c) {
        __syncthreads();            // prior chunk's B-reads done
        storeW();
        __syncthreads();            // images visible

        const int dt = c >> 2, kk = c & 3;
        const int off = (dt * N_ + nn[kk]) * D_;

        if (c < 19) loadW(c + 1);   // prefetch next chunk during MFMAs

        #pragma unroll
        for (int s2 = 0; s2 < 2; ++s2) {
            short8 ah[2], al[2];
            #pragma unroll
            for (int rt = 0; rt < 2; ++rt) {
                ah[rt] = *(const short8*)(xhrow[rt] + off + s2 * 32 + dseg);
                al[rt] = *(const short8*)(xlrow[rt] + off + s2 * 32 + dseg);
            }
            #pragma unroll
            for (int cf = 0; cf < 4; ++cf) {
                short8 bh = bfrag(s2, cf, 0);
                short8 bl = bfrag(s2, cf, 1);
                #pragma unroll
                for (int rt = 0; rt < 2; ++rt) {
                    acc1[rt][cf] = __builtin_amdgcn_mfma_f32_16x16x32_bf16(ah[rt], bh, acc1[rt][cf], 0, 0, 0);
                    acc1[rt][cf] = __builtin_amdgcn_mfma_f32_16x16x32_bf16(ah[rt], bl, acc1[rt][cf], 0, 0, 0);
                    acc1[rt][cf] = __builtin_amdgcn_mfma_f32_16x16x32_bf16(al[rt], bh, acc1[rt][cf], 0, 0, 0);
                }
            }
        }
    }

    // ---------------- h1 = relu(acc1 + b1) -> split bf16 LDS; stage W2 ------
    loadW(20);
    __syncthreads();                // last chunk's B-reads done
    storeW();
    const int ccol = L & 15;
    const int qrow = (L >> 4) * 4;
    #pragma unroll
    for (int cf = 0; cf < 4; ++cf) {
        float bv = b1[(size_t)ne * H_ + cf * 16 + ccol];
        #pragma unroll
        for (int rt = 0; rt < 2; ++rt)
            #pragma unroll
            for (int reg = 0; reg < 4; ++reg) {
                int r = w * 32 + rt * 16 + qrow + reg;      // wave-private rows
                float hv = fmaxf(acc1[rt][cf][reg] + bv, 0.f);
                unsigned hi, lo;
                split2(hv, hi, lo);
                h1h[r][cf * 16 + ccol] = (short)hi;
                h1l[r][cf * 16 + ccol] = (short)lo;
            }
    }
    __syncthreads();                // W2 images visible (h rows are wave-private)

    // ---------------- GEMM2: h1 @ W2 (K=64) ----------------
    float4v acc2[2][4];
    #pragma unroll
    for (int rt = 0; rt < 2; ++rt)
        #pragma unroll
        for (int cf = 0; cf < 4; ++cf) acc2[rt][cf] = (float4v)0.f;

    loadW(21);                      // prefetch W3 during GEMM2 MFMAs
    #pragma unroll
    for (int s2 = 0; s2 < 2; ++s2) {
        short8 ah[2], al[2];
        #pragma unroll
        for (int rt = 0; rt < 2; ++rt) {
            ah[rt] = *(const short8*)&h1h[w * 32 + rt * 16 + lrow][s2 * 32 + dseg];
            al[rt] = *(const short8*)&h1l[w * 32 + rt * 16 + lrow][s2 * 32 + dseg];
        }
        #pragma unroll
        for (int cf = 0; cf < 4; ++cf) {
            short8 bh = bfrag(s2, cf, 0);
            short8 bl = bfrag(s2, cf, 1);
            #pragma unroll
            for (int rt = 0; rt < 2; ++rt) {
                acc2[rt][cf] = __builtin_amdgcn_mfma_f32_16x16x32_bf16(ah[rt], bh, acc2[rt][cf], 0, 0, 0);
                acc2[rt][cf] = __builtin_amdgcn_mfma_f32_16x16x32_bf16(ah[rt], bl, acc2[rt][cf], 0, 0, 0);
                acc2[rt][cf] = __builtin_amdgcn_mfma_f32_16x16x32_bf16(al[rt], bh, acc2[rt][cf], 0, 0, 0);
            }
        }
    }

    // ---------------- h2 = relu(acc2 + b2) -> split bf16 LDS; stage W3 ------
    __syncthreads();                // all waves done reading W2 images
    storeW();
    #pragma unroll
    for (int cf = 0; cf < 4; ++cf) {
        float bv = b2[(size_t)ne * H_ + cf * 16 + ccol];
        #pragma unroll
        for (int rt = 0; rt < 2; ++rt)
            #pragma unroll
            for (int reg = 0; reg < 4; ++reg) {
                int r = w * 32 + rt * 16 + qrow + reg;
                float hv = fmaxf(acc2[rt][cf][reg] + bv, 0.f);
                unsigned hi, lo;
                split2(hv, hi, lo);
                h1h[r][cf * 16 + ccol] = (short)hi;
                h1l[r][cf * 16 + ccol] = (short)lo;
            }
    }
    __syncthreads();                // W3 images visible

    // ---------------- GEMM3: h2 @ W3 -> pred; err epilogue ----------------
    float4v acc3[2][4];
    #pragma unroll
    for (int rt = 0; rt < 2; ++rt)
        #pragma unroll
        for (int cf = 0; cf < 4; ++cf) acc3[rt][cf] = (float4v)0.f;

    #pragma unroll
    for (int s2 = 0; s2 < 2; ++s2) {
        short8 ah[2], al[2];
        #pragma unroll
        for (int rt = 0; rt < 2; ++rt) {
            ah[rt] = *(const short8*)&h1h[w * 32 + rt * 16 + lrow][s2 * 32 + dseg];
            al[rt] = *(const short8*)&h1l[w * 32 + rt * 16 + lrow][s2 * 32 + dseg];
        }
        #pragma unroll
        for (int cf = 0; cf < 4; ++cf) {
            short8 bh = bfrag(s2, cf, 0);
            short8 bl = bfrag(s2, cf, 1);
            #pragma unroll
            for (int rt = 0; rt < 2; ++rt) {
                acc3[rt][cf] = __builtin_amdgcn_mfma_f32_16x16x32_bf16(ah[rt], bh, acc3[rt][cf], 0, 0, 0);
                acc3[rt][cf] = __builtin_amdgcn_mfma_f32_16x16x32_bf16(ah[rt], bl, acc3[rt][cf], 0, 0, 0);
                acc3[rt][cf] = __builtin_amdgcn_mfma_f32_16x16x32_bf16(al[rt], bh, acc3[rt][cf], 0, 0, 0);
            }
        }
    }

    float b3v[4];
    #pragma unroll
    for (int cf = 0; cf < 4; ++cf) b3v[cf] = b3[(size_t)ne * D_ + cf * 16 + ccol];

    #pragma unroll
    for (int rt = 0; rt < 2; ++rt) {
        float s[4] = {0.f, 0.f, 0.f, 0.f};
        #pragma unroll
        for (int reg = 0; reg < 4; ++reg) {
            int m  = rowbase + rt * 16 + qrow + reg;
            int mc = m < M_ ? m : M_ - 1;
            int b = mc / TW, t = mc % TW;
            const float* yp = x + ((size_t)(b * T_ + t + 2) * N_ + n) * D_;
            #pragma unroll
            for (int cf = 0; cf < 4; ++cf) {
                float d = acc3[rt][cf][reg] + b3v[cf] - yp[cf * 16 + ccol];
                s[reg] += d * d;
            }
        }
        #pragma unroll
        for (int reg = 0; reg < 4; ++reg) {
            s[reg] += __shfl_xor(s[reg], 1);
            s[reg] += __shfl_xor(s[reg], 2);
            s[reg] += __shfl_xor(s[reg], 4);
            s[reg] += __shfl_xor(s[reg], 8);
        }
        if (ccol == 0) {
            #pragma unroll
            for (int reg = 0; reg < 4; ++reg) {
                int m = rowbase + rt * 16 + qrow + reg;
                if (m < M_) err_ws[((size_t)m * N_ + n) * E_ + e] = s[reg] * (1.f / 64.f);
            }
        }
    }
}

// ---------------------------------------------------------------------------
// Reduce: per (m,n) min/argmin over E, softmax(-err) KL; block atomicAdd.
__global__ __launch_bounds__(256) void moe_reduce_kernel(
    const float* __restrict__ err_ws, float* __restrict__ out)
{
    const int tid = threadIdx.x;
    const int idx = blockIdx.x * 256 + tid;
    float v = 0.f;
    if (idx < M_ * N_) {
        const int m = idx / N_, n = idx % N_;
        const float* ep = err_ws + (size_t)idx * E_;
        float ev[E_];
        float mn = ep[0];
        int am = 0;
        ev[0] = mn;
        #pragma unroll
        for (int i = 1; i < E_; ++i) {
            ev[i] = ep[i];
            if (ev[i] < mn) { mn = ev[i]; am = i; }
        }
        float p[E_];
        float Z = 0.f;
        #pragma unroll
        for (int i = 0; i < E_; ++i) { p[i] = expf(mn - ev[i]); Z += p[i]; }
        const float invZ = 1.f / Z;
        float kl = 0.f;
        #pragma unroll
        for (int i = 0; i < E_; ++i) {
            float q = p[i] * invZ;
            kl += q * (logf(q + 1e-9f) + 2.0794415416798357f);  // log(8)
        }
        v = mn + 0.01f * kl;
        const int t = m % TW, b = m / TW;
        if (t == TW - 1 && n == N_ - 1) out[1 + b] = (float)am;
    }
    __shared__ float sd[256];
    sd[tid] = v;
    __syncthreads();
    for (int s = 128; s > 0; s >>= 1) {
        if (tid < s) sd[tid] += sd[tid + s];
        __syncthreads();
    }
    if (tid == 0) atomicAdd(out, sd[0] * (1.f / 20160.f));  // / B / (N-1) / (T-4)
}

__global__ void init_out_kernel(float* out)
{
    if (threadIdx.x == 0) out[0] = 0.f;
}

extern "C" void kernel_launch(void* const* d_in, const int* in_sizes, int n_in,
                              void* d_out, int out_size, void* d_ws, size_t ws_size,
                              hipStream_t stream)
{
    const float* x  = (const float*)d_in[0];
    const int*   nb = (const int*)d_in[1];
    const float* W1 = (const float*)d_in[2];
    const float* b1 = (const float*)d_in[3];
    const float* W2 = (const float*)d_in[4];
    const float* b2 = (const float*)d_in[5];
    const float* W3 = (const float*)d_in[6];
    const float* b3 = (const float*)d_in[7];
    float* out    = (float*)d_out;
    float* err_ws = (float*)d_ws;
    char*  wimg   = (char*)d_ws + WIMG_OFF;
    short* xh     = (short*)((char*)d_ws + XH_OFF);
    short* xl     = (short*)((char*)d_ws + XL_OFF);

    hipLaunchKernelGGL(init_out_kernel, dim3(1), dim3(64), 0, stream, out);
    hipLaunchKernelGGL(wimg_kernel, dim3(7744), dim3(256), 0, stream, W1, W2, W3, wimg);
    hipLaunchKernelGGL(xsplit_kernel, dim3(1408), dim3(256), 0, stream, x, xh, xl);
    hipLaunchKernelGGL(moe_err_kernel, dim3(NE_ * NT2), dim3(256), 0, stream,
                       x, xh, xl, nb, b1, b2, b3, wimg, err_ws);
    const int nred = (M_ * N_ + 255) / 256;
    hipLaunchKernelGGL(moe_reduce_kernel, dim3(nred), dim3(256), 0, stream, err_ws, out);
}